// Round 7
// baseline (190.722 us; speedup 1.0000x reference)
//
#include <hip/hip_runtime.h>
#include <cstdint>
#include <cstddef>

#define NB 32
#define NG 30
#define NA 8400
#define NC 80
#define SELB 512        // k_sel block size
#define MGRIDX 33       // ceil(NA/256)
#define NBLK (MGRIDX * NB)
#define LCAP 128        // LDS candidate list cap; in_both <= 75 provably
                        // (in_ctr is a strict 5-cell window per axis -> <=25/lvl)
#define NITER 17        // ceil(NA/SELB)

typedef unsigned long long u64;

struct Params {
  const float* f8; const float* f16; const float* f32; const float* lab;
  float*    bbox;    // [NB*NA] float4 decoded cx,cy,w,h
  float*    objlog;  // [NB*NA] raw obj logit
  float*    po;      // [NB*NA] sigm(objlog)
  float*    base_;   // [NB*NA] -sum_c log(1-sqrt(pc*po)+eps)  (candidates only!)
  uint2*    gob;     // [NB*NA] x: bits 0..29 in_both(g), bit31 anchor_ok
                     //          y: bit g = (pred box overlaps gt g) && anchor_ok
  unsigned* mmask;   // [NB*NA] bit g set => anchor popped for gt g (pre-dedup)
  float*    part;    // [NBLK] float4 per-block partial (iou, obj, cls, nfg)
  float*    out;     // [1] final loss
};

__device__ __forceinline__ float fsigm(float x) {
  return __fdividef(1.0f, 1.0f + __expf(-x));
}

__device__ __forceinline__ void anchor_geom(int a, int& x, int& y, int& W, int& hw,
                                            float& stride, int& lvl) {
  if (a < 6400)      { W = 80; hw = 6400; stride = 8.f;  lvl = 0; int i = a;        y = i / 80; x = i - y * 80; }
  else if (a < 8000) { W = 40; hw = 1600; stride = 16.f; lvl = 1; int i = a - 6400; y = i / 40; x = i - y * 40; }
  else               { W = 20; hw = 400;  stride = 32.f; lvl = 2; int i = a - 8000; y = i / 20; x = i - y * 20; }
}

__device__ __forceinline__ float pair_iou(float px, float py, float pw, float ph,
                                          float glx, float gty, float grx, float gby,
                                          float area_g) {
  float tlx = fmaxf(glx, px - pw * 0.5f);
  float tly = fmaxf(gty, py - ph * 0.5f);
  float brx = fminf(grx, px + pw * 0.5f);
  float bry = fminf(gby, py + ph * 0.5f);
  float inter = ((tlx < brx) && (tly < bry)) ? (brx - tlx) * (bry - tly) : 0.0f;
  return __fdividef(inter, area_g + pw * ph - inter + 1e-16f);
}

// THE cost expression — single definition, inlined into k_sel and k_match.
__device__ __forceinline__ float cost_of(float4 pb, float po, float bs, unsigned gb,
                                         int g, float glx, float gty, float grx,
                                         float gby, float area_g, float xl,
                                         float& iou_out) {
  bool ok = (gb >> 31) & 1u;
  float iou = pair_iou(pb.x, pb.y, pb.z, pb.w, glx, gty, grx, gby, area_g);
  iou = ok ? iou : 0.0f;
  float iou_cost = -__logf(iou + 1e-8f);
  float pc = fsigm(xl);
  float pr = sqrtf(pc * po);
  float cls_cost = bs - (__logf(pr + 1e-8f) - __logf(1.0f - pr + 1e-8f));
  float c = cls_cost + 3.0f * iou_cost;
  c = c + (((gb >> g) & 1u) ? 0.0f : 100000.0f);
  c = c + (ok ? 0.0f : 1000000000.0f);
  iou_out = iou;
  return c;
}

// monotone float -> sortable u32, packed with anchor idx: u64 order == lex order
__device__ __forceinline__ u64 packkey(float c, int a) {
  unsigned b = __float_as_uint(c);
  b = (b & 0x80000000u) ? ~b : (b | 0x80000000u);
  return ((u64)b << 32) | (unsigned)a;
}

// Inline base_ computation (cold-path only; identical serial order to k_stage).
__device__ float base_of(const Params& p, int b, int a, float po) {
  int lvl = (a < 6400) ? 0 : (a < 8000) ? 1 : 2;
  int hw  = (lvl == 0) ? 6400 : (lvl == 1) ? 1600 : 400;
  int loff = (lvl == 0) ? 0 : (lvl == 1) ? 6400 : 8000;
  const float* f = (lvl == 0) ? p.f8 : (lvl == 1) ? p.f16 : p.f32;
  int cb = b * 85 * hw + 5 * hw + (a - loff);
  float bs = 0.0f;
#pragma unroll 1
  for (int c = 0; c < NC; c++) {
    float xl = f[cb + c * hw];
    float pc = fsigm(xl);
    float pr = sqrtf(pc * po);
    bs -= __logf(1.0f - pr + 1e-8f);
  }
  return bs;
}

// K1: per (b,a): decode, po, gate/overlap bits, sparse per-thread base_ for
// candidates. base_ loop is staged 16-wide: 16 independent strided loads
// issued per batch before the serial FP chain consumes them (MLP; the rolled
// form kept only ~2 loads in flight at VGPR=28 -> latency-bound stragglers).
// FP accumulation order unchanged (c ascending) -> bit-identical.
__global__ __launch_bounds__(256) void k_stage(Params p) {
  __shared__ float sglx[NG], sgrx[NG], sgty[NG], sgby[NG], sgx[NG], sgy[NG];
  int b = blockIdx.y;
  int tid = threadIdx.x;
  if (tid < NG) {
    const float* gt = p.lab + (b * NG + tid) * 5;
    float gx = gt[0], gy = gt[1], gw = gt[2], gh = gt[3];
    sgx[tid] = gx; sgy[tid] = gy;
    sglx[tid] = gx - 0.5f * gw; sgrx[tid] = gx + 0.5f * gw;   // same arithmetic
    sgty[tid] = gy - 0.5f * gh; sgby[tid] = gy + 0.5f * gh;   // as reference
  }
  __syncthreads();
  int a = blockIdx.x * 256 + tid;
  if (a >= NA) return;
  p.mmask[b * NA + a] = 0u;

  int x, y, W, hw, lvl; float stride;
  anchor_geom(a, x, y, W, hw, stride, lvl);
  const float* f = (lvl == 0) ? p.f8 : (lvl == 1) ? p.f16 : p.f32;
  int loff = (lvl == 0) ? 0 : (lvl == 1) ? 6400 : 8000;
  int fb = b * 85 * hw + (a - loff);

  float tx = f[fb];
  float ty = f[fb + hw];
  float tw = f[fb + 2 * hw];
  float th = f[fb + 3 * hw];
  float ob = f[fb + 4 * hw];

  float px = (tx + (float)x) * stride;
  float py = (ty + (float)y) * stride;
  float pw = __expf(tw) * stride;
  float ph = __expf(th) * stride;
  ((float4*)p.bbox)[b * NA + a] = make_float4(px, py, pw, ph);
  p.objlog[b * NA + a] = ob;
  float po_r = fsigm(ob);
  p.po[b * NA + a] = po_r;

  float xc = ((float)x + 0.5f) * stride;
  float yc = ((float)y + 0.5f) * stride;
  float r = 2.5f * stride;
  float plx = px - 0.5f * pw, prx = px + 0.5f * pw;
  float pty = py - 0.5f * ph, pby = py + 0.5f * ph;
  unsigned gb = 0, ov = 0; int ok = 0;
#pragma unroll
  for (int g = 0; g < NG; g++) {
    float glx = sglx[g], grx = sgrx[g], gty_ = sgty[g], gby = sgby[g];
    float gx = sgx[g], gy = sgy[g];
    bool inb = (xc > glx) && (xc < grx) && (yc > gty_) && (yc < gby);
    bool inc = (xc > gx - r) && (xc < gx + r) && (yc > gy - r) && (yc < gy + r);
    ok |= (inb || inc) ? 1 : 0;
    gb |= (unsigned)(inb && inc) << g;
    // exact "iou != 0" predicate: pred box strictly overlaps gt box
    bool o = (fmaxf(glx, plx) < fminf(grx, prx)) && (fmaxf(gty_, pty) < fminf(gby, pby));
    ov |= (unsigned)o << g;
  }
  unsigned gbw = gb | ((unsigned)ok << 31);
  p.gob[b * NA + a] = make_uint2(gbw, ok ? ov : 0u);

  // base_ only for in_both candidates (~1200 of 268800 threads, clustered)
  if (gb & 0x3FFFFFFFu) {
    int cb = fb + 5 * hw;
    float bs = 0.0f;
#pragma unroll 1
    for (int c0 = 0; c0 < NC; c0 += 16) {
      float xv[16];                      // static-indexed -> registers
#pragma unroll
      for (int j = 0; j < 16; j++) xv[j] = f[cb + (c0 + j) * hw];
#pragma unroll
      for (int j = 0; j < 16; j++) {     // same serial order as the reference
        float pc = fsigm(xv[j]);
        float pr = sqrtf(pc * po_r);
        bs -= __logf(1.0f - pr + 1e-8f);
      }
    }
    p.base_[b * NA + a] = bs;
  }
}

// block-wide min of u64 key; result on ALL threads. (SELB threads)
__device__ __forceinline__ u64 block_min_u64(u64 k, int tid, u64* swk) {
#pragma unroll
  for (int off = 32; off; off >>= 1) {
    u64 k2 = __shfl_down(k, off, 64);
    if (k2 < k) k = k2;
  }
  int wv = tid >> 6;
  if ((tid & 63) == 0) swk[wv] = k;
  __syncthreads();
  u64 m = swk[0];
#pragma unroll
  for (int w = 1; w < SELB / 64; w++) if (swk[w] < m) m = swk[w];
  __syncthreads();
  return m;
}

// K2: one block per (b,g).
//  phase A: gather ious of overlap-bit anchors + in_both candidates into LDS
//  top-10 iou rounds -> dyn_k
//  phase B: cost for the <=75 in_both candidates only, pop dyn_k lex-minima
//  cold fallback: exact rescan if dyn_k > candidate count (provably ~never)
__global__ __launch_bounds__(SELB) void k_sel(Params p) {
  __shared__ float sh_iou[NA];          // 33.6 KB -> 4 blocks/CU
  __shared__ unsigned sh_cand[LCAP];
  __shared__ float swv[SELB / 64];
  __shared__ int   swi[SELB / 64];
  __shared__ u64   swk[SELB / 64];
  __shared__ int   sh_excl[10];
  __shared__ int   scnt, scand;
  int bg = blockIdx.x;
  int b = bg / NG, g = bg % NG;
  int tid = threadIdx.x;
  if (tid == 0) { scnt = 0; scand = 0; }

  const float* gt = p.lab + (b * NG + g) * 5;
  float gx = gt[0], gy = gt[1], gw = gt[2], gh = gt[3];
  int cg = (int)gt[4];
  float glx = gx - 0.5f * gw, grx = gx + 0.5f * gw;
  float gty = gy - 0.5f * gh, gby = gy + 0.5f * gh;
  float area_g = gw * gh;
  const float4* bb  = (const float4*)p.bbox + b * NA;
  const uint2*  gov = p.gob + b * NA;
  __syncthreads();

  // ---- phase A: sparse iou gather + candidate gather (wave-ballot compact) ----
  int lane = tid & 63;
  for (int it = 0; it < NITER; it++) {
    int a = it * SELB + tid;
    unsigned ob = 0u, gbw = 0u;
    if (a < NA) { uint2 v = gov[a]; gbw = v.x; ob = v.y; }
    bool act = (ob >> g) & 1u;
    bool cnd = (gbw >> g) & 1u;
    u64 bal = __ballot(act);
    if (bal) {                       // per-wave skip of empty 64-anchor spans
      int leader = __ffsll(bal) - 1;
      int basec = 0;
      if (lane == leader) basec = atomicAdd(&scnt, __popcll(bal));
      basec = __shfl(basec, leader, 64);
      if (act) {
        int pre = __popcll(bal & ((1ull << lane) - 1ull));
        float4 pb = bb[a];
        float iou = pair_iou(pb.x, pb.y, pb.z, pb.w, glx, gty, grx, gby, area_g);
        sh_iou[basec + pre] = iou;
      }
    }
    u64 bc = __ballot(cnd);
    if (bc) {
      int leader = __ffsll(bc) - 1;
      int basec = 0;
      if (lane == leader) basec = atomicAdd(&scand, __popcll(bc));
      basec = __shfl(basec, leader, 64);
      if (cnd) {
        int s = basec + __popcll(bc & ((1ull << lane) - 1ull));
        if (s < LCAP) sh_cand[s] = (unsigned)a;
      }
    }
  }
  __syncthreads();
  int n = scnt;

  // ---- top-10 iou sum (descending, matching ref order) -> dyn_k ----
  float sum = 0.0f;
  for (int rnd = 0; rnd < 10; rnd++) {
    float mv = -1.0f; int mi = -1;
    for (int j = tid; j < n; j += SELB) {
      float v = sh_iou[j];
      if (v > mv) { mv = v; mi = j; }
    }
#pragma unroll
    for (int off = 32; off; off >>= 1) {
      float v2 = __shfl_down(mv, off, 64);
      int   i2 = __shfl_down(mi, off, 64);
      if (v2 > mv) { mv = v2; mi = i2; }
    }
    if ((tid & 63) == 0) { swv[tid >> 6] = mv; swi[tid >> 6] = mi; }
    __syncthreads();
    float bv = swv[0]; int bi = swi[0];
#pragma unroll
    for (int w = 1; w < SELB / 64; w++)
      if (swv[w] > bv) { bv = swv[w]; bi = swi[w]; }
    sum += fmaxf(bv, 0.0f);          // empty pops contribute ref's zero padding
    if (tid == 0 && bi >= 0) sh_iou[bi] = -1.0f;
    __syncthreads();
  }
  int dynk = (int)sum;
  if (dynk < 1) dynk = 1;

  // ---- phase B: cost only for the in_both candidates (all cheaper than any
  //      non-in_both cost by the +100000 penalty gap -> exact when nc>=dynk) ----
  int nc = scand; if (nc > LCAP) nc = LCAP;
  u64 key = ~0ull;
  if (tid < nc) {
    int a = (int)sh_cand[tid];
    float4 pb = bb[a];
    float po_ = p.po[b * NA + a];
    float bs_ = p.base_[b * NA + a];
    unsigned gb_ = gov[a].x;
    int lvl = (a < 6400) ? 0 : (a < 8000) ? 1 : 2;
    int hw  = (lvl == 0) ? 6400 : (lvl == 1) ? 1600 : 400;
    int loff = (lvl == 0) ? 0 : (lvl == 1) ? 6400 : 8000;
    const float* f = (lvl == 0) ? p.f8 : (lvl == 1) ? p.f16 : p.f32;
    float xl = f[b * 85 * hw + (5 + cg) * hw + (a - loff)];
    float iou_;
    float c = cost_of(pb, po_, bs_, gb_, g, glx, gty, grx, gby, area_g, xl, iou_);
    key = packkey(c, a);
  }
  unsigned* mrow = p.mmask + b * NA;
  unsigned gbit = 1u << g;
  int matched = 0;
  for (int it = 0; it < dynk; it++) {
    u64 win = block_min_u64(key, tid, swk);
    if (win == ~0ull) break;
    if (key == win) {                 // idx embedded => unique owner
      atomicOr(&mrow[(unsigned)(win & 0xFFFFFFFFu)], gbit);
      key = ~0ull;
    }
    matched++;
  }

  // ---- cold exact fallback: dyn_k exceeded candidate count ----
  if (matched < dynk) {
    const float* pov = p.po + b * NA;
    for (int it = matched; it < dynk; it++) {
      u64 best = ~0ull;
      for (int al = tid; al < NA; al += SELB) {
        unsigned gb = gov[al].x;
        if (!(gb >> 31)) continue;          // matching &= anchor_ok
        if ((gb >> g) & 1u) continue;       // in_both already matched above
        bool skip = false;
        for (int e = matched; e < it; e++) if (sh_excl[e] == al) skip = true;
        if (skip) continue;
        float po_ = pov[al];
        float bs = base_of(p, b, al, po_);
        int lvl = (al < 6400) ? 0 : (al < 8000) ? 1 : 2;
        int hw  = (lvl == 0) ? 6400 : (lvl == 1) ? 1600 : 400;
        int loff = (lvl == 0) ? 0 : (lvl == 1) ? 6400 : 8000;
        const float* f = (lvl == 0) ? p.f8 : (lvl == 1) ? p.f16 : p.f32;
        float xl = f[b * 85 * hw + (5 + cg) * hw + (al - loff)];
        float4 pb = bb[al];
        float iou_;
        float c = cost_of(pb, po_, bs, gb, g, glx, gty, grx, gby, area_g, xl, iou_);
        u64 nk = packkey(c, al);
        if (nk < best) best = nk;
      }
      u64 win = block_min_u64(best, tid, swk);
      if (win == ~0ull) break;
      int aw = (int)(win & 0xFFFFFFFFu);
      if (best == win) {
        atomicOr(&mrow[aw], gbit);
        p.base_[b * NA + aw] = base_of(p, b, aw, pov[aw]);  // for k_match dedup
      }
      if (tid == 0) sh_excl[it] = aw;
      __syncthreads();
    }
  }
}

__device__ __forceinline__ float block_sum(float val, volatile float* sw) {
#pragma unroll
  for (int off = 32; off > 0; off >>= 1) val += __shfl_down(val, off, 64);
  int lane = threadIdx.x & 63, wv = threadIdx.x >> 6;
  __syncthreads();
  if (lane == 0) sw[wv] = val;
  __syncthreads();
  float r = 0.0f;
  if (threadIdx.x == 0) r = sw[0] + sw[1] + sw[2] + sw[3];
  return r;
}

// K3: per (b,a) dedup (wave-coop cost recompute for am>1) + losses.
// NO contended atomics, NO device fences: per-block partial to a private slot.
__global__ __launch_bounds__(256) void k_match(Params p) {
  __shared__ float sred[4];
  int b = blockIdx.y;
  int tid = threadIdx.x;
  int lane = tid & 63;
  int a = blockIdx.x * 256 + tid;
  bool valid = a < NA;

  float l_iou = 0.0f, l_obj = 0.0f, l_cls = 0.0f, l_nfg = 0.0f;
  unsigned mask = 0; int am = 0;
  bool fg = false; float pred_iou = 0.0f; int cg_ = 0;

  if (valid) {
    mask = p.mmask[b * NA + a];
    am = __popc(mask);
    fg = (mask != 0u);
    float ol = p.objlog[b * NA + a];
    float tfg = fg ? 1.0f : 0.0f;
    l_obj = fmaxf(ol, 0.0f) - ol * tfg + __logf(1.0f + __expf(-fabsf(ol)));
  }

  // wave-coop dedup: lanes 0..29 recompute the cost column, lex argmin (cost,g)
  unsigned long long amb = __ballot(valid && am > 1);
  while (amb) {
    int src = __ffsll(amb) - 1;
    amb &= amb - 1ull;
    int aa = __shfl(a, src, 64);
    float4 pb = ((const float4*)p.bbox)[b * NA + aa];
    float po_ = p.po[b * NA + aa];
    float bs_ = p.base_[b * NA + aa];
    unsigned gb_ = p.gob[b * NA + aa].x;

    int lvl = (aa < 6400) ? 0 : (aa < 8000) ? 1 : 2;
    int hw  = (lvl == 0) ? 6400 : (lvl == 1) ? 1600 : 400;
    int loff = (lvl == 0) ? 0 : (lvl == 1) ? 6400 : 8000;
    const float* f = (lvl == 0) ? p.f8 : (lvl == 1) ? p.f16 : p.f32;
    int cb = b * 85 * hw + 5 * hw + (aa - loff);

    float c = 3.4e38f; int gg = 0x7FFFFFFF;
    if (lane < NG) {
      const float* gtg = p.lab + (b * NG + lane) * 5;
      float gx = gtg[0], gy = gtg[1], gw = gtg[2], gh = gtg[3];
      int cg = (int)gtg[4];
      float xl = f[cb + cg * hw];
      float iou_;
      c = cost_of(pb, po_, bs_, gb_, lane,
                  gx - 0.5f * gw, gy - 0.5f * gh,
                  gx + 0.5f * gw, gy + 0.5f * gh, gw * gh, xl, iou_);
      gg = lane;
    }
#pragma unroll
    for (int off = 32; off; off >>= 1) {
      float c2 = __shfl_down(c, off, 64);
      int   g2 = __shfl_down(gg, off, 64);
      if (c2 < c || (c2 == c && g2 < gg)) { c = c2; gg = g2; }
    }
    gg = __shfl(gg, 0, 64);
    if (lane == src) mask = 1u << gg;
  }

  if (valid && fg) {
    l_nfg = 1.0f;
    int mg = __ffs(mask) - 1;
    const float* gtm = p.lab + (b * NG + mg) * 5;
    float gx = gtm[0], gy = gtm[1], gw = gtm[2], gh = gtm[3];
    cg_ = (int)gtm[4];
    float4 pb = ((const float4*)p.bbox)[b * NA + a];
    float iou = pair_iou(pb.x, pb.y, pb.z, pb.w,
                         gx - 0.5f * gw, gy - 0.5f * gh,
                         gx + 0.5f * gw, gy + 0.5f * gh, gw * gh);
    pred_iou = iou;
    l_iou = 1.0f - iou * iou;
  }

  // wave-cooperative cls-loss for fg anchors
  unsigned long long fgb = __ballot(valid && fg);
  while (fgb) {
    int src = __ffsll(fgb) - 1;
    fgb &= fgb - 1ull;
    int   aa   = __shfl(a, src, 64);
    float piou = __shfl(pred_iou, src, 64);
    int   ccg  = __shfl(cg_, src, 64);

    int lvl = (aa < 6400) ? 0 : (aa < 8000) ? 1 : 2;
    int hw  = (lvl == 0) ? 6400 : (lvl == 1) ? 1600 : 400;
    int loff = (lvl == 0) ? 0 : (lvl == 1) ? 6400 : 8000;
    const float* f = (lvl == 0) ? p.f8 : (lvl == 1) ? p.f16 : p.f32;
    int cb = b * 85 * hw + 5 * hw + (aa - loff);

    float part = 0.0f;
#pragma unroll
    for (int c0 = 0; c0 < NC; c0 += 64) {
      int c = c0 + lane;
      if (c < NC) {
        float xl = f[cb + c * hw];
        float t = (c == ccg) ? piou : 0.0f;
        part += fmaxf(xl, 0.0f) - xl * t + __logf(1.0f + __expf(-fabsf(xl)));
      }
    }
#pragma unroll
    for (int off = 32; off; off >>= 1) part += __shfl_down(part, off, 64);
    if (lane == 0) l_cls += part;
  }

  float s0 = block_sum(l_iou, sred);
  float s1 = block_sum(l_obj, sred);
  float s2 = block_sum(l_cls, sred);
  float s3 = block_sum(l_nfg, sred);
  if (tid == 0) {
    ((float4*)p.part)[b * MGRIDX + blockIdx.x] = make_float4(s0, s1, s2, s3);
  }
}

// K4: single block sums the per-block partials and writes the loss.
__global__ __launch_bounds__(256) void k_final(Params p) {
  __shared__ float sred[4];
  int tid = threadIdx.x;
  float s0 = 0.0f, s1 = 0.0f, s2 = 0.0f, s3 = 0.0f;
  for (int i = tid; i < NBLK; i += 256) {
    float4 v = ((const float4*)p.part)[i];
    s0 += v.x; s1 += v.y; s2 += v.z; s3 += v.w;
  }
  s0 = block_sum(s0, sred);
  s1 = block_sum(s1, sred);
  s2 = block_sum(s2, sred);
  s3 = block_sum(s3, sred);
  if (tid == 0) {
    p.out[0] = (5.0f * s0 + 0.1f * s1 + s2) / fmaxf(s3, 1.0f);
  }
}

extern "C" void kernel_launch(void* const* d_in, const int* in_sizes, int n_in,
                              void* d_out, int out_size, void* d_ws, size_t ws_size,
                              hipStream_t stream) {
  Params p;
  p.f8  = (const float*)d_in[0];
  p.f16 = (const float*)d_in[1];
  p.f32 = (const float*)d_in[2];
  p.lab = (const float*)d_in[3];

  float* w = (float*)d_ws;
  p.bbox   = w;              w += (size_t)NB * NA * 4;
  p.objlog = w;              w += (size_t)NB * NA;
  p.po     = w;              w += (size_t)NB * NA;
  p.base_  = w;              w += (size_t)NB * NA;
  p.gob    = (uint2*)w;      w += (size_t)NB * NA * 2;   // 8B-aligned (even floats)
  p.mmask  = (unsigned*)w;   w += (size_t)NB * NA;
  p.part   = w;              w += (size_t)NBLK * 4;
  p.out    = (float*)d_out;

  dim3 gd(MGRIDX, NB);
  k_stage<<<gd, 256, 0, stream>>>(p);
  k_sel  <<<NB * NG, SELB, 0, stream>>>(p);
  k_match<<<gd, 256, 0, stream>>>(p);
  k_final<<<1, 256, 0, stream>>>(p);
}

// Round 8
// 183.517 us; speedup vs baseline: 1.0393x; 1.0393x over previous
//
#include <hip/hip_runtime.h>
#include <cstdint>
#include <cstddef>

#define NB 32
#define NG 30
#define NA 8400
#define NC 80
#define SELB 512        // k_sel block size
#define MGRIDX 33       // ceil(NA/256)
#define NBLK (MGRIDX * NB)
#define LCAP 128        // LDS candidate list cap; in_both <= 75 provably
                        // (in_ctr is a strict 5-cell window per axis -> <=25/lvl)
#define NITER 17        // ceil(NA/SELB)

typedef unsigned long long u64;

struct Params {
  const float* f8; const float* f16; const float* f32; const float* lab;
  float*    bbox;    // [NB*NA] float4 decoded cx,cy,w,h
  float*    objlog;  // [NB*NA] raw obj logit
  float*    po;      // [NB*NA] sigm(objlog)
  float*    base_;   // [NB*NA] -sum_c log(1-sqrt(pc*po)+eps)  (candidates only!)
  uint2*    gob;     // [NB*NA] x: bits 0..29 in_both(g), bit31 anchor_ok
                     //          y: bit g = (pred box overlaps gt g) && anchor_ok
  unsigned* mmask;   // [NB*NA] bit g set => anchor popped for gt g (pre-dedup)
  float*    part;    // [NBLK] float4 per-block partial (iou, obj, cls, nfg)
  float*    out;     // [1] final loss
};

__device__ __forceinline__ float fsigm(float x) {
  return __fdividef(1.0f, 1.0f + __expf(-x));
}

__device__ __forceinline__ void anchor_geom(int a, int& x, int& y, int& W, int& hw,
                                            float& stride, int& lvl) {
  if (a < 6400)      { W = 80; hw = 6400; stride = 8.f;  lvl = 0; int i = a;        y = i / 80; x = i - y * 80; }
  else if (a < 8000) { W = 40; hw = 1600; stride = 16.f; lvl = 1; int i = a - 6400; y = i / 40; x = i - y * 40; }
  else               { W = 20; hw = 400;  stride = 32.f; lvl = 2; int i = a - 8000; y = i / 20; x = i - y * 20; }
}

__device__ __forceinline__ float pair_iou(float px, float py, float pw, float ph,
                                          float glx, float gty, float grx, float gby,
                                          float area_g) {
  float tlx = fmaxf(glx, px - pw * 0.5f);
  float tly = fmaxf(gty, py - ph * 0.5f);
  float brx = fminf(grx, px + pw * 0.5f);
  float bry = fminf(gby, py + ph * 0.5f);
  float inter = ((tlx < brx) && (tly < bry)) ? (brx - tlx) * (bry - tly) : 0.0f;
  return __fdividef(inter, area_g + pw * ph - inter + 1e-16f);
}

// THE cost expression — single definition, inlined into k_sel and k_match.
__device__ __forceinline__ float cost_of(float4 pb, float po, float bs, unsigned gb,
                                         int g, float glx, float gty, float grx,
                                         float gby, float area_g, float xl,
                                         float& iou_out) {
  bool ok = (gb >> 31) & 1u;
  float iou = pair_iou(pb.x, pb.y, pb.z, pb.w, glx, gty, grx, gby, area_g);
  iou = ok ? iou : 0.0f;
  float iou_cost = -__logf(iou + 1e-8f);
  float pc = fsigm(xl);
  float pr = sqrtf(pc * po);
  float cls_cost = bs - (__logf(pr + 1e-8f) - __logf(1.0f - pr + 1e-8f));
  float c = cls_cost + 3.0f * iou_cost;
  c = c + (((gb >> g) & 1u) ? 0.0f : 100000.0f);
  c = c + (ok ? 0.0f : 1000000000.0f);
  iou_out = iou;
  return c;
}

// monotone float -> sortable u32, packed with anchor idx: u64 order == lex order
__device__ __forceinline__ u64 packkey(float c, int a) {
  unsigned b = __float_as_uint(c);
  b = (b & 0x80000000u) ? ~b : (b | 0x80000000u);
  return ((u64)b << 32) | (unsigned)a;
}

// Inline base_ computation (cold-path only; identical serial order to k_stage).
__device__ float base_of(const Params& p, int b, int a, float po) {
  int lvl = (a < 6400) ? 0 : (a < 8000) ? 1 : 2;
  int hw  = (lvl == 0) ? 6400 : (lvl == 1) ? 1600 : 400;
  int loff = (lvl == 0) ? 0 : (lvl == 1) ? 6400 : 8000;
  const float* f = (lvl == 0) ? p.f8 : (lvl == 1) ? p.f16 : p.f32;
  int cb = b * 85 * hw + 5 * hw + (a - loff);
  float bs = 0.0f;
#pragma unroll 1
  for (int c = 0; c < NC; c++) {
    float xl = f[cb + c * hw];
    float pc = fsigm(xl);
    float pr = sqrtf(pc * po);
    bs -= __logf(1.0f - pr + 1e-8f);
  }
  return bs;
}

// K1: per (b,a): decode, po, gate/overlap bits, sparse per-thread base_ for
// candidates. base_ loop: 5 fully-unrolled batches of {16 independent loads,
// sched_barrier(0), 16-term serial chain}. The fence pins all 16 loads above
// the first use -> 16-deep MLP (r7 showed the scheduler otherwise collapses
// the batch: VGPR stayed 32, loads interleaved with uses, 1 miss exposed per
// class). FP accumulation order unchanged (c ascending) -> bit-identical.
__global__ __launch_bounds__(256) void k_stage(Params p) {
  __shared__ float sglx[NG], sgrx[NG], sgty[NG], sgby[NG], sgx[NG], sgy[NG];
  int b = blockIdx.y;
  int tid = threadIdx.x;
  if (tid < NG) {
    const float* gt = p.lab + (b * NG + tid) * 5;
    float gx = gt[0], gy = gt[1], gw = gt[2], gh = gt[3];
    sgx[tid] = gx; sgy[tid] = gy;
    sglx[tid] = gx - 0.5f * gw; sgrx[tid] = gx + 0.5f * gw;   // same arithmetic
    sgty[tid] = gy - 0.5f * gh; sgby[tid] = gy + 0.5f * gh;   // as reference
  }
  __syncthreads();
  int a = blockIdx.x * 256 + tid;
  if (a >= NA) return;
  p.mmask[b * NA + a] = 0u;

  int x, y, W, hw, lvl; float stride;
  anchor_geom(a, x, y, W, hw, stride, lvl);
  const float* f = (lvl == 0) ? p.f8 : (lvl == 1) ? p.f16 : p.f32;
  int loff = (lvl == 0) ? 0 : (lvl == 1) ? 6400 : 8000;
  int fb = b * 85 * hw + (a - loff);

  float tx = f[fb];
  float ty = f[fb + hw];
  float tw = f[fb + 2 * hw];
  float th = f[fb + 3 * hw];
  float ob = f[fb + 4 * hw];

  float px = (tx + (float)x) * stride;
  float py = (ty + (float)y) * stride;
  float pw = __expf(tw) * stride;
  float ph = __expf(th) * stride;
  ((float4*)p.bbox)[b * NA + a] = make_float4(px, py, pw, ph);
  p.objlog[b * NA + a] = ob;
  float po_r = fsigm(ob);
  p.po[b * NA + a] = po_r;

  float xc = ((float)x + 0.5f) * stride;
  float yc = ((float)y + 0.5f) * stride;
  float r = 2.5f * stride;
  float plx = px - 0.5f * pw, prx = px + 0.5f * pw;
  float pty = py - 0.5f * ph, pby = py + 0.5f * ph;
  unsigned gb = 0, ov = 0; int ok = 0;
#pragma unroll
  for (int g = 0; g < NG; g++) {
    float glx = sglx[g], grx = sgrx[g], gty_ = sgty[g], gby = sgby[g];
    float gx = sgx[g], gy = sgy[g];
    bool inb = (xc > glx) && (xc < grx) && (yc > gty_) && (yc < gby);
    bool inc = (xc > gx - r) && (xc < gx + r) && (yc > gy - r) && (yc < gy + r);
    ok |= (inb || inc) ? 1 : 0;
    gb |= (unsigned)(inb && inc) << g;
    // exact "iou != 0" predicate: pred box strictly overlaps gt box
    bool o = (fmaxf(glx, plx) < fminf(grx, prx)) && (fmaxf(gty_, pty) < fminf(gby, pby));
    ov |= (unsigned)o << g;
  }
  unsigned gbw = gb | ((unsigned)ok << 31);
  p.gob[b * NA + a] = make_uint2(gbw, ok ? ov : 0u);

  // base_ only for in_both candidates (~1200 of 268800 threads, clustered)
  if (gb & 0x3FFFFFFFu) {
    int cb = fb + 5 * hw;
    float bs = 0.0f;
#pragma unroll
    for (int c0 = 0; c0 < NC; c0 += 16) {
      float xv[16];                      // static-indexed -> registers
#pragma unroll
      for (int j = 0; j < 16; j++) xv[j] = f[cb + (c0 + j) * hw];
      __builtin_amdgcn_sched_barrier(0); // pin: all 16 loads issue before use
#pragma unroll
      for (int j = 0; j < 16; j++) {     // same serial order as the reference
        float pc = fsigm(xv[j]);
        float pr = sqrtf(pc * po_r);
        bs -= __logf(1.0f - pr + 1e-8f);
      }
    }
    p.base_[b * NA + a] = bs;
  }
}

// block-wide min of u64 key; result on ALL threads. (SELB threads)
__device__ __forceinline__ u64 block_min_u64(u64 k, int tid, u64* swk) {
#pragma unroll
  for (int off = 32; off; off >>= 1) {
    u64 k2 = __shfl_down(k, off, 64);
    if (k2 < k) k = k2;
  }
  int wv = tid >> 6;
  if ((tid & 63) == 0) swk[wv] = k;
  __syncthreads();
  u64 m = swk[0];
#pragma unroll
  for (int w = 1; w < SELB / 64; w++) if (swk[w] < m) m = swk[w];
  __syncthreads();
  return m;
}

// K2: one block per (b,g).
//  phase A: gather ious of overlap-bit anchors + in_both candidates into LDS
//  top-10 iou rounds -> dyn_k
//  phase B: cost for the <=75 in_both candidates only, pop dyn_k lex-minima
//  cold fallback: exact rescan if dyn_k > candidate count (provably ~never)
__global__ __launch_bounds__(SELB) void k_sel(Params p) {
  __shared__ float sh_iou[NA];          // 33.6 KB -> 4 blocks/CU
  __shared__ unsigned sh_cand[LCAP];
  __shared__ float swv[SELB / 64];
  __shared__ int   swi[SELB / 64];
  __shared__ u64   swk[SELB / 64];
  __shared__ int   sh_excl[10];
  __shared__ int   scnt, scand;
  int bg = blockIdx.x;
  int b = bg / NG, g = bg % NG;
  int tid = threadIdx.x;
  if (tid == 0) { scnt = 0; scand = 0; }

  const float* gt = p.lab + (b * NG + g) * 5;
  float gx = gt[0], gy = gt[1], gw = gt[2], gh = gt[3];
  int cg = (int)gt[4];
  float glx = gx - 0.5f * gw, grx = gx + 0.5f * gw;
  float gty = gy - 0.5f * gh, gby = gy + 0.5f * gh;
  float area_g = gw * gh;
  const float4* bb  = (const float4*)p.bbox + b * NA;
  const uint2*  gov = p.gob + b * NA;
  __syncthreads();

  // ---- phase A: sparse iou gather + candidate gather (wave-ballot compact) ----
  int lane = tid & 63;
  for (int it = 0; it < NITER; it++) {
    int a = it * SELB + tid;
    unsigned ob = 0u, gbw = 0u;
    if (a < NA) { uint2 v = gov[a]; gbw = v.x; ob = v.y; }
    bool act = (ob >> g) & 1u;
    bool cnd = (gbw >> g) & 1u;
    u64 bal = __ballot(act);
    if (bal) {                       // per-wave skip of empty 64-anchor spans
      int leader = __ffsll(bal) - 1;
      int basec = 0;
      if (lane == leader) basec = atomicAdd(&scnt, __popcll(bal));
      basec = __shfl(basec, leader, 64);
      if (act) {
        int pre = __popcll(bal & ((1ull << lane) - 1ull));
        float4 pb = bb[a];
        float iou = pair_iou(pb.x, pb.y, pb.z, pb.w, glx, gty, grx, gby, area_g);
        sh_iou[basec + pre] = iou;
      }
    }
    u64 bc = __ballot(cnd);
    if (bc) {
      int leader = __ffsll(bc) - 1;
      int basec = 0;
      if (lane == leader) basec = atomicAdd(&scand, __popcll(bc));
      basec = __shfl(basec, leader, 64);
      if (cnd) {
        int s = basec + __popcll(bc & ((1ull << lane) - 1ull));
        if (s < LCAP) sh_cand[s] = (unsigned)a;
      }
    }
  }
  __syncthreads();
  int n = scnt;

  // ---- top-10 iou sum (descending, matching ref order) -> dyn_k ----
  float sum = 0.0f;
  for (int rnd = 0; rnd < 10; rnd++) {
    float mv = -1.0f; int mi = -1;
    for (int j = tid; j < n; j += SELB) {
      float v = sh_iou[j];
      if (v > mv) { mv = v; mi = j; }
    }
#pragma unroll
    for (int off = 32; off; off >>= 1) {
      float v2 = __shfl_down(mv, off, 64);
      int   i2 = __shfl_down(mi, off, 64);
      if (v2 > mv) { mv = v2; mi = i2; }
    }
    if ((tid & 63) == 0) { swv[tid >> 6] = mv; swi[tid >> 6] = mi; }
    __syncthreads();
    float bv = swv[0]; int bi = swi[0];
#pragma unroll
    for (int w = 1; w < SELB / 64; w++)
      if (swv[w] > bv) { bv = swv[w]; bi = swi[w]; }
    sum += fmaxf(bv, 0.0f);          // empty pops contribute ref's zero padding
    if (tid == 0 && bi >= 0) sh_iou[bi] = -1.0f;
    __syncthreads();
  }
  int dynk = (int)sum;
  if (dynk < 1) dynk = 1;

  // ---- phase B: cost only for the in_both candidates (all cheaper than any
  //      non-in_both cost by the +100000 penalty gap -> exact when nc>=dynk) ----
  int nc = scand; if (nc > LCAP) nc = LCAP;
  u64 key = ~0ull;
  if (tid < nc) {
    int a = (int)sh_cand[tid];
    float4 pb = bb[a];
    float po_ = p.po[b * NA + a];
    float bs_ = p.base_[b * NA + a];
    unsigned gb_ = gov[a].x;
    int lvl = (a < 6400) ? 0 : (a < 8000) ? 1 : 2;
    int hw  = (lvl == 0) ? 6400 : (lvl == 1) ? 1600 : 400;
    int loff = (lvl == 0) ? 0 : (lvl == 1) ? 6400 : 8000;
    const float* f = (lvl == 0) ? p.f8 : (lvl == 1) ? p.f16 : p.f32;
    float xl = f[b * 85 * hw + (5 + cg) * hw + (a - loff)];
    float iou_;
    float c = cost_of(pb, po_, bs_, gb_, g, glx, gty, grx, gby, area_g, xl, iou_);
    key = packkey(c, a);
  }
  unsigned* mrow = p.mmask + b * NA;
  unsigned gbit = 1u << g;
  int matched = 0;
  for (int it = 0; it < dynk; it++) {
    u64 win = block_min_u64(key, tid, swk);
    if (win == ~0ull) break;
    if (key == win) {                 // idx embedded => unique owner
      atomicOr(&mrow[(unsigned)(win & 0xFFFFFFFFu)], gbit);
      key = ~0ull;
    }
    matched++;
  }

  // ---- cold exact fallback: dyn_k exceeded candidate count ----
  if (matched < dynk) {
    const float* pov = p.po + b * NA;
    for (int it = matched; it < dynk; it++) {
      u64 best = ~0ull;
      for (int al = tid; al < NA; al += SELB) {
        unsigned gb = gov[al].x;
        if (!(gb >> 31)) continue;          // matching &= anchor_ok
        if ((gb >> g) & 1u) continue;       // in_both already matched above
        bool skip = false;
        for (int e = matched; e < it; e++) if (sh_excl[e] == al) skip = true;
        if (skip) continue;
        float po_ = pov[al];
        float bs = base_of(p, b, al, po_);
        int lvl = (al < 6400) ? 0 : (al < 8000) ? 1 : 2;
        int hw  = (lvl == 0) ? 6400 : (lvl == 1) ? 1600 : 400;
        int loff = (lvl == 0) ? 0 : (lvl == 1) ? 6400 : 8000;
        const float* f = (lvl == 0) ? p.f8 : (lvl == 1) ? p.f16 : p.f32;
        float xl = f[b * 85 * hw + (5 + cg) * hw + (al - loff)];
        float4 pb = bb[al];
        float iou_;
        float c = cost_of(pb, po_, bs, gb, g, glx, gty, grx, gby, area_g, xl, iou_);
        u64 nk = packkey(c, al);
        if (nk < best) best = nk;
      }
      u64 win = block_min_u64(best, tid, swk);
      if (win == ~0ull) break;
      int aw = (int)(win & 0xFFFFFFFFu);
      if (best == win) {
        atomicOr(&mrow[aw], gbit);
        p.base_[b * NA + aw] = base_of(p, b, aw, pov[aw]);  // for k_match dedup
      }
      if (tid == 0) sh_excl[it] = aw;
      __syncthreads();
    }
  }
}

__device__ __forceinline__ float block_sum(float val, volatile float* sw) {
#pragma unroll
  for (int off = 32; off > 0; off >>= 1) val += __shfl_down(val, off, 64);
  int lane = threadIdx.x & 63, wv = threadIdx.x >> 6;
  __syncthreads();
  if (lane == 0) sw[wv] = val;
  __syncthreads();
  float r = 0.0f;
  if (threadIdx.x == 0) r = sw[0] + sw[1] + sw[2] + sw[3];
  return r;
}

// K3: per (b,a) dedup (wave-coop cost recompute for am>1) + losses.
// NO contended atomics, NO device fences: per-block partial to a private slot.
__global__ __launch_bounds__(256) void k_match(Params p) {
  __shared__ float sred[4];
  int b = blockIdx.y;
  int tid = threadIdx.x;
  int lane = tid & 63;
  int a = blockIdx.x * 256 + tid;
  bool valid = a < NA;

  float l_iou = 0.0f, l_obj = 0.0f, l_cls = 0.0f, l_nfg = 0.0f;
  unsigned mask = 0; int am = 0;
  bool fg = false; float pred_iou = 0.0f; int cg_ = 0;

  if (valid) {
    mask = p.mmask[b * NA + a];
    am = __popc(mask);
    fg = (mask != 0u);
    float ol = p.objlog[b * NA + a];
    float tfg = fg ? 1.0f : 0.0f;
    l_obj = fmaxf(ol, 0.0f) - ol * tfg + __logf(1.0f + __expf(-fabsf(ol)));
  }

  // wave-coop dedup: lanes 0..29 recompute the cost column, lex argmin (cost,g)
  unsigned long long amb = __ballot(valid && am > 1);
  while (amb) {
    int src = __ffsll(amb) - 1;
    amb &= amb - 1ull;
    int aa = __shfl(a, src, 64);
    float4 pb = ((const float4*)p.bbox)[b * NA + aa];
    float po_ = p.po[b * NA + aa];
    float bs_ = p.base_[b * NA + aa];
    unsigned gb_ = p.gob[b * NA + aa].x;

    int lvl = (aa < 6400) ? 0 : (aa < 8000) ? 1 : 2;
    int hw  = (lvl == 0) ? 6400 : (lvl == 1) ? 1600 : 400;
    int loff = (lvl == 0) ? 0 : (lvl == 1) ? 6400 : 8000;
    const float* f = (lvl == 0) ? p.f8 : (lvl == 1) ? p.f16 : p.f32;
    int cb = b * 85 * hw + 5 * hw + (aa - loff);

    float c = 3.4e38f; int gg = 0x7FFFFFFF;
    if (lane < NG) {
      const float* gtg = p.lab + (b * NG + lane) * 5;
      float gx = gtg[0], gy = gtg[1], gw = gtg[2], gh = gtg[3];
      int cg = (int)gtg[4];
      float xl = f[cb + cg * hw];
      float iou_;
      c = cost_of(pb, po_, bs_, gb_, lane,
                  gx - 0.5f * gw, gy - 0.5f * gh,
                  gx + 0.5f * gw, gy + 0.5f * gh, gw * gh, xl, iou_);
      gg = lane;
    }
#pragma unroll
    for (int off = 32; off; off >>= 1) {
      float c2 = __shfl_down(c, off, 64);
      int   g2 = __shfl_down(gg, off, 64);
      if (c2 < c || (c2 == c && g2 < gg)) { c = c2; gg = g2; }
    }
    gg = __shfl(gg, 0, 64);
    if (lane == src) mask = 1u << gg;
  }

  if (valid && fg) {
    l_nfg = 1.0f;
    int mg = __ffs(mask) - 1;
    const float* gtm = p.lab + (b * NG + mg) * 5;
    float gx = gtm[0], gy = gtm[1], gw = gtm[2], gh = gtm[3];
    cg_ = (int)gtm[4];
    float4 pb = ((const float4*)p.bbox)[b * NA + a];
    float iou = pair_iou(pb.x, pb.y, pb.z, pb.w,
                         gx - 0.5f * gw, gy - 0.5f * gh,
                         gx + 0.5f * gw, gy + 0.5f * gh, gw * gh);
    pred_iou = iou;
    l_iou = 1.0f - iou * iou;
  }

  // wave-cooperative cls-loss for fg anchors
  unsigned long long fgb = __ballot(valid && fg);
  while (fgb) {
    int src = __ffsll(fgb) - 1;
    fgb &= fgb - 1ull;
    int   aa   = __shfl(a, src, 64);
    float piou = __shfl(pred_iou, src, 64);
    int   ccg  = __shfl(cg_, src, 64);

    int lvl = (aa < 6400) ? 0 : (aa < 8000) ? 1 : 2;
    int hw  = (lvl == 0) ? 6400 : (lvl == 1) ? 1600 : 400;
    int loff = (lvl == 0) ? 0 : (lvl == 1) ? 6400 : 8000;
    const float* f = (lvl == 0) ? p.f8 : (lvl == 1) ? p.f16 : p.f32;
    int cb = b * 85 * hw + 5 * hw + (aa - loff);

    float part = 0.0f;
#pragma unroll
    for (int c0 = 0; c0 < NC; c0 += 64) {
      int c = c0 + lane;
      if (c < NC) {
        float xl = f[cb + c * hw];
        float t = (c == ccg) ? piou : 0.0f;
        part += fmaxf(xl, 0.0f) - xl * t + __logf(1.0f + __expf(-fabsf(xl)));
      }
    }
#pragma unroll
    for (int off = 32; off; off >>= 1) part += __shfl_down(part, off, 64);
    if (lane == 0) l_cls += part;
  }

  float s0 = block_sum(l_iou, sred);
  float s1 = block_sum(l_obj, sred);
  float s2 = block_sum(l_cls, sred);
  float s3 = block_sum(l_nfg, sred);
  if (tid == 0) {
    ((float4*)p.part)[b * MGRIDX + blockIdx.x] = make_float4(s0, s1, s2, s3);
  }
}

// K4: single block sums the per-block partials and writes the loss.
__global__ __launch_bounds__(256) void k_final(Params p) {
  __shared__ float sred[4];
  int tid = threadIdx.x;
  float s0 = 0.0f, s1 = 0.0f, s2 = 0.0f, s3 = 0.0f;
  for (int i = tid; i < NBLK; i += 256) {
    float4 v = ((const float4*)p.part)[i];
    s0 += v.x; s1 += v.y; s2 += v.z; s3 += v.w;
  }
  s0 = block_sum(s0, sred);
  s1 = block_sum(s1, sred);
  s2 = block_sum(s2, sred);
  s3 = block_sum(s3, sred);
  if (tid == 0) {
    p.out[0] = (5.0f * s0 + 0.1f * s1 + s2) / fmaxf(s3, 1.0f);
  }
}

extern "C" void kernel_launch(void* const* d_in, const int* in_sizes, int n_in,
                              void* d_out, int out_size, void* d_ws, size_t ws_size,
                              hipStream_t stream) {
  Params p;
  p.f8  = (const float*)d_in[0];
  p.f16 = (const float*)d_in[1];
  p.f32 = (const float*)d_in[2];
  p.lab = (const float*)d_in[3];

  float* w = (float*)d_ws;
  p.bbox   = w;              w += (size_t)NB * NA * 4;
  p.objlog = w;              w += (size_t)NB * NA;
  p.po     = w;              w += (size_t)NB * NA;
  p.base_  = w;              w += (size_t)NB * NA;
  p.gob    = (uint2*)w;      w += (size_t)NB * NA * 2;   // 8B-aligned (even floats)
  p.mmask  = (unsigned*)w;   w += (size_t)NB * NA;
  p.part   = w;              w += (size_t)NBLK * 4;
  p.out    = (float*)d_out;

  dim3 gd(MGRIDX, NB);
  k_stage<<<gd, 256, 0, stream>>>(p);
  k_sel  <<<NB * NG, SELB, 0, stream>>>(p);
  k_match<<<gd, 256, 0, stream>>>(p);
  k_final<<<1, 256, 0, stream>>>(p);
}